// Round 1
// baseline (548.266 us; speedup 1.0000x reference)
//
#include <hip/hip_runtime.h>

// Unfold (im2col) for IN_SHAPE=(4,64,224,224), K=3x3, pad=1, stride=1, dil=1
// with the reference's nh=k+dil=4 quirk -> output spatial 223x223.
// out[((b*64+c)*9 + i*3 + j)*49729 + oh*223 + ow] = x[b,c,oh+i-1,ow+j-1] (0-pad)
//
// Memory-bound: 458 MB write + 51 MB read. Strategy: flat-index float4 stores
// (16B aligned, dwordx4), incremental index decode to avoid per-element divides.

#define TOTAL_ELEMS 114575616u   // 4*576*49729
#define N_VEC4      28643904u    // TOTAL_ELEMS / 4 (exact)
#define PLANE_IN    50176u       // 224*224

__global__ __launch_bounds__(256) void unfold223_kernel(
    const float* __restrict__ x, float* __restrict__ out)
{
    unsigned int t = blockIdx.x * 256u + threadIdx.x;   // float4 index
    if (t >= N_VEC4) return;
    unsigned int n = t * 4u;                            // flat element index

    // Full decode of element 0 (compiler emits magic-mul division sequences).
    unsigned int ch  = n / 49729u;           // output channel: (b*64+c)*9 + i*3 + j
    unsigned int pos = n - ch * 49729u;      // oh*223 + ow
    unsigned int oh  = pos / 223u;
    unsigned int ow  = pos - oh * 223u;
    unsigned int q   = ch / 9u;              // b*64 + c
    unsigned int r   = ch - q * 9u;          // i*3 + j
    unsigned int i   = r / 3u;
    unsigned int j   = r - i * 3u;

    float v[4];
#pragma unroll
    for (int e = 0; e < 4; ++e) {
        int ih = (int)(oh + i) - 1;
        int iw = (int)(ow + j) - 1;
        bool valid = ((unsigned)ih < 224u) && ((unsigned)iw < 224u);
        // branch-free: clamp address to a safe location, select 0 afterwards
        unsigned int cih = valid ? (unsigned)ih : 0u;
        unsigned int ciw = valid ? (unsigned)iw : 0u;
        float val = x[q * PLANE_IN + cih * 224u + ciw];
        v[e] = valid ? val : 0.0f;

        // incremental decode for the next element (carry chain of selects)
        ow++;
        if (ow == 223u) {
            ow = 0u; oh++;
            if (oh == 223u) {
                oh = 0u; j++;
                if (j == 3u) {
                    j = 0u; i++;
                    if (i == 3u) { i = 0u; q++; }
                }
            }
        }
    }

    reinterpret_cast<float4*>(out)[t] = make_float4(v[0], v[1], v[2], v[3]);
}

extern "C" void kernel_launch(void* const* d_in, const int* in_sizes, int n_in,
                              void* d_out, int out_size, void* d_ws, size_t ws_size,
                              hipStream_t stream)
{
    const float* x = (const float*)d_in[0];
    float* out = (float*)d_out;
    unsigned int blocks = (N_VEC4 + 255u) / 256u;   // 111,891
    unfold223_kernel<<<dim3(blocks), dim3(256), 0, stream>>>(x, out);
}